// Round 1
// baseline (947.487 us; speedup 1.0000x reference)
//
#include <hip/hip_runtime.h>
#include <math.h>

#define NB 64
#define NA 256
#define NM 16
#define HA 256
#define NF 16
#define NCONV 3
#define NCLS 6
#define EPSB 1e-5f

// ---------------- prep: pack weights ----------------
// Wcat[l][k][o] (k<256, o<1024): o<512 -> W1=W_full[l][k][o], else W2=W_full[l][256+k][o-512]
// W3cat[l][k][o] (k<16, o<512) = W_full[l][512+k][o]
__global__ void prep_weights(const float* __restrict__ Wf,
                             float* __restrict__ Wcat, float* __restrict__ W3cat) {
  int i = blockIdx.x * 256 + threadIdx.x;
  const int TOT1 = NCONV * HA * 1024;
  if (i < TOT1) {
    int l = i / (HA * 1024);
    int r = i - l * (HA * 1024);
    int k = r >> 10, o = r & 1023;
    int row = (o < 512) ? k : (HA + k);
    int col = (o < 512) ? o : (o - 512);
    Wcat[i] = Wf[(l * 528 + row) * 512 + col];
  }
  const int TOT2 = NCONV * NF * 512;
  if (i < TOT2) {
    int l = i / (NF * 512);
    int r = i - l * (NF * 512);
    int k = r >> 9, o = r & 511;
    W3cat[i] = Wf[(l * 528 + 512 + k) * 512 + o];
  }
}

// Gaussian expansion table G[b,n,m,f] = exp(-(d - 0.2 f)^2 / 0.04)
__global__ void gauss_kernel(const float* __restrict__ dist, float* __restrict__ G) {
  int i = blockIdx.x * 256 + threadIdx.x;  // NB*NA*NM*NF exact
  int r = i >> 4, f = i & 15;
  float d = dist[r];
  float x = d - 0.2f * (float)f;
  G[i] = expf(-x * x * 25.0f);
}

__global__ void init_atom(const float* __restrict__ emb, float* __restrict__ atom) {
  int i = blockIdx.x * 256 + threadIdx.x;  // NB*NA*HA exact
  atom[i] = emb[i & (NA * HA - 1)];
}

// ---------------- GEMM: A[Mrows][256] @ Bmat[256][1024] -> C[Mrows][1024], f32 ----------------
// 128x128 tile, BK=16, 256 threads, 8x8 microtile (cols split as tx*4 and 64+tx*4 for LDS bank spread)
__global__ __launch_bounds__(256) void gemm_f32(const float* __restrict__ Amat,
                                                const float* __restrict__ Bmat,
                                                float* __restrict__ Cmat, int Mrows) {
  __shared__ float As[16][136];   // [k][row], pad 136 keeps 16B align + bank spread
  __shared__ float Bs[16][128];   // [k][col]
  int t = threadIdx.x;
  int tx = t & 15, ty = t >> 4;
  int rowBase = blockIdx.y * 128;
  int colBase = blockIdx.x * 128;
  float acc[8][8];
#pragma unroll
  for (int i = 0; i < 8; ++i)
#pragma unroll
    for (int j = 0; j < 8; ++j) acc[i][j] = 0.f;

  for (int k0 = 0; k0 < HA; k0 += 16) {
#pragma unroll
    for (int cc = 0; cc < 2; ++cc) {  // stage A: 512 float4 chunks
      int c = t + cc * 256;
      int row = c >> 2;
      int koff = (c & 3) << 2;
      float4 av = *(const float4*)&Amat[(rowBase + row) * HA + k0 + koff];
      As[koff + 0][row] = av.x; As[koff + 1][row] = av.y;
      As[koff + 2][row] = av.z; As[koff + 3][row] = av.w;
    }
#pragma unroll
    for (int cc = 0; cc < 2; ++cc) {  // stage B
      int c = t + cc * 256;
      int k = c >> 5;
      int col = (c & 31) << 2;
      *(float4*)&Bs[k][col] = *(const float4*)&Bmat[(k0 + k) * 1024 + colBase + col];
    }
    __syncthreads();
#pragma unroll
    for (int k = 0; k < 16; ++k) {
      float a[8], bfr[8];
      *(float4*)&a[0] = *(const float4*)&As[k][ty * 8];
      *(float4*)&a[4] = *(const float4*)&As[k][ty * 8 + 4];
      *(float4*)&bfr[0] = *(const float4*)&Bs[k][tx * 4];
      *(float4*)&bfr[4] = *(const float4*)&Bs[k][64 + tx * 4];
#pragma unroll
      for (int i = 0; i < 8; ++i)
#pragma unroll
        for (int j = 0; j < 8; ++j) acc[i][j] += a[i] * bfr[j];
    }
    __syncthreads();
  }
#pragma unroll
  for (int i = 0; i < 8; ++i) {
    int r = rowBase + ty * 8 + i;
    float4 v0 = make_float4(acc[i][0], acc[i][1], acc[i][2], acc[i][3]);
    float4 v1 = make_float4(acc[i][4], acc[i][5], acc[i][6], acc[i][7]);
    *(float4*)&Cmat[r * 1024 + colBase + tx * 4] = v0;
    *(float4*)&Cmat[r * 1024 + colBase + 64 + tx * 4] = v1;
  }
}

// ---------------- pass A: assemble z rows, accumulate BN1 stats ----------------
// block = 256 thr handles 8 n's x 16 m's; thread t owns features o=t (filter) and o=t+256 (core)
// z[o] = H[self, o] + H[nbr, 512+o] + G.W3[:,o]   (bias dropped: BN-invariant)
__global__ __launch_bounds__(256) void pass_a(const float* __restrict__ H,
                                              const float* __restrict__ G,
                                              const int* __restrict__ adj,
                                              const float* __restrict__ W3,
                                              float* __restrict__ bn1, int batched) {
  __shared__ float gg[NM][NF];
  __shared__ int ji[NM];
  int t = threadIdx.x;
  int b = blockIdx.y;
  int n0 = blockIdx.x * 8;
  float w3a[NF], w3b[NF];
#pragma unroll
  for (int k = 0; k < NF; ++k) {
    w3a[k] = W3[k * 512 + t];
    w3b[k] = W3[k * 512 + 256 + t];
  }
  int hbase = batched ? b * NA : 0;
  float s1a = 0.f, s2a = 0.f, s1b = 0.f, s2b = 0.f;
  for (int nn = 0; nn < 8; ++nn) {
    int n = n0 + nn;
    int grow = (b * NA + n) * NM;
    __syncthreads();
    gg[t >> 4][t & 15] = G[grow * NF + t];
    if (t < NM) ji[t] = adj[grow + t];
    __syncthreads();
    float x1a = H[(hbase + n) * 1024 + t];
    float x1b = H[(hbase + n) * 1024 + 256 + t];
#pragma unroll
    for (int m = 0; m < NM; ++m) {
      int j = ji[m];
      const float* hr = &H[(hbase + j) * 1024 + 512];
      float ya = hr[t], yb = hr[256 + t];
      float ga = 0.f, gb = 0.f;
#pragma unroll
      for (int k = 0; k < NF; ++k) {
        float g = gg[m][k];
        ga += g * w3a[k];
        gb += g * w3b[k];
      }
      float za = x1a + ya + ga;
      float zb = x1b + yb + gb;
      s1a += za; s2a += za * za;
      s1b += zb; s2b += zb * zb;
    }
  }
  atomicAdd(&bn1[t], s1a);
  atomicAdd(&bn1[256 + t], s1b);
  atomicAdd(&bn1[512 + t], s2a);
  atomicAdd(&bn1[512 + 256 + t], s2b);
}

__global__ void finalize1(const float* __restrict__ bn1, const float* __restrict__ g,
                          const float* __restrict__ beta, float* __restrict__ coef) {
  int t = threadIdx.x;  // 512
  const float inv = 1.0f / (float)(NB * NA * NM);
  float mu = bn1[t] * inv;
  float var = bn1[512 + t] * inv - mu * mu;
  float sc = g[t] * rsqrtf(var + EPSB);
  coef[t] = sc;
  coef[512 + t] = beta[t] - mu * sc;
}

// ---------------- pass B: recompute z, BN1+sigmoid*relu, sum over m, BN2 stats ----------------
__global__ __launch_bounds__(256) void pass_b(const float* __restrict__ H,
                                              const float* __restrict__ G,
                                              const int* __restrict__ adj,
                                              const float* __restrict__ W3,
                                              const float* __restrict__ coef,
                                              float* __restrict__ nbr,
                                              float* __restrict__ bn2, int batched) {
  __shared__ float gg[NM][NF];
  __shared__ int ji[NM];
  int t = threadIdx.x;
  int b = blockIdx.y;
  int n0 = blockIdx.x * 8;
  float w3a[NF], w3b[NF];
#pragma unroll
  for (int k = 0; k < NF; ++k) {
    w3a[k] = W3[k * 512 + t];
    w3b[k] = W3[k * 512 + 256 + t];
  }
  float scf = coef[t], shf = coef[512 + t];
  float scc = coef[256 + t], shc = coef[512 + 256 + t];
  int hbase = batched ? b * NA : 0;
  float sB1 = 0.f, sB2 = 0.f;
  for (int nn = 0; nn < 8; ++nn) {
    int n = n0 + nn;
    int grow = (b * NA + n) * NM;
    __syncthreads();
    gg[t >> 4][t & 15] = G[grow * NF + t];
    if (t < NM) ji[t] = adj[grow + t];
    __syncthreads();
    float x1a = H[(hbase + n) * 1024 + t];
    float x1b = H[(hbase + n) * 1024 + 256 + t];
    float acc = 0.f;
#pragma unroll
    for (int m = 0; m < NM; ++m) {
      int j = ji[m];
      const float* hr = &H[(hbase + j) * 1024 + 512];
      float ya = hr[t], yb = hr[256 + t];
      float ga = 0.f, gb = 0.f;
#pragma unroll
      for (int k = 0; k < NF; ++k) {
        float g = gg[m][k];
        ga += g * w3a[k];
        gb += g * w3b[k];
      }
      float za = x1a + ya + ga;
      float zb = x1b + yb + gb;
      float yf = za * scf + shf;
      float yc = zb * scc + shc;
      float sig = 1.0f / (1.0f + expf(-yf));
      float core = fmaxf(yc, 0.f);
      acc += sig * core;
    }
    nbr[(b * NA + n) * HA + t] = acc;
    sB1 += acc;
    sB2 += acc * acc;
  }
  atomicAdd(&bn2[t], sB1);
  atomicAdd(&bn2[256 + t], sB2);
}

__global__ void finalize2(const float* __restrict__ bn2, const float* __restrict__ g,
                          const float* __restrict__ beta, float* __restrict__ coef2) {
  int t = threadIdx.x;  // 256
  const float inv = 1.0f / (float)(NB * NA);
  float mu = bn2[t] * inv;
  float var = bn2[256 + t] * inv - mu * mu;
  float sc = g[t] * rsqrtf(var + EPSB);
  coef2[t] = sc;
  coef2[256 + t] = beta[t] - mu * sc;
}

__global__ void pass_c(float* __restrict__ atom, const float* __restrict__ nbr,
                       const float* __restrict__ coef2) {
  int i = blockIdx.x * 256 + threadIdx.x;  // NB*NA*HA exact
  int o = i & (HA - 1);
  float v = atom[i] + nbr[i] * coef2[o] + coef2[256 + o];
  atom[i] = fmaxf(v, 0.f);
}

// ---------------- epilogue: pool over n, classifier, softmax ----------------
__global__ __launch_bounds__(256) void epilogue(const float* __restrict__ atom,
                                                const float* __restrict__ Wc,
                                                const float* __restrict__ bc,
                                                float* __restrict__ out) {
  __shared__ float pooled[HA];
  __shared__ float lg[NCLS];
  int b = blockIdx.x, t = threadIdx.x;
  float s = 0.f;
  for (int n = 0; n < NA; ++n) s += atom[(b * NA + n) * HA + t];
  pooled[t] = s * (1.0f / (float)NA);
  __syncthreads();
  if (t < NCLS) {
    float a = bc[t];
    for (int o = 0; o < HA; ++o) a += pooled[o] * Wc[o * NCLS + t];
    lg[t] = a;
  }
  __syncthreads();
  if (t == 0) {
    float mx = lg[0];
    for (int c = 1; c < NCLS; ++c) mx = fmaxf(mx, lg[c]);
    float e[NCLS], den = 0.f;
    for (int c = 0; c < NCLS; ++c) { e[c] = expf(lg[c] - mx); den += e[c]; }
    for (int c = 0; c < NCLS; ++c) out[b * NCLS + c] = e[c] / den;
  }
}

extern "C" void kernel_launch(void* const* d_in, const int* in_sizes, int n_in,
                              void* d_out, int out_size, void* d_ws, size_t ws_size,
                              hipStream_t stream) {
  const float* dist = (const float*)d_in[0];
  const int* adj = (const int*)d_in[1];
  const float* emb = (const float*)d_in[2];
  const float* Wf = (const float*)d_in[3];
  // d_in[4] = b_full: dropped (BN-invariant)
  const float* gh = (const float*)d_in[5];
  const float* bh = (const float*)d_in[6];
  const float* go = (const float*)d_in[7];
  const float* bo = (const float*)d_in[8];
  const float* Wc = (const float*)d_in[9];
  const float* bc = (const float*)d_in[10];
  float* out = (float*)d_out;

  char* p = (char*)d_ws;
  float* G = (float*)p;     p += (size_t)NB * NA * NM * NF * 4;   // 16 MB
  float* H = (float*)p;     p += (size_t)NB * NA * 1024 * 4;      // 64 MB
  float* H0 = (float*)p;    p += (size_t)NA * 1024 * 4;           // 1 MB
  float* atom = (float*)p;  p += (size_t)NB * NA * HA * 4;        // 16 MB
  float* nbr = (float*)p;   p += (size_t)NB * NA * HA * 4;        // 16 MB
  float* Wcat = (float*)p;  p += (size_t)NCONV * HA * 1024 * 4;   // 3 MB
  float* W3cat = (float*)p; p += (size_t)NCONV * NF * 512 * 4;
  float* bn1 = (float*)p;   p += 1024 * 4;
  float* bn2 = (float*)p;   p += 512 * 4;
  float* coef1 = (float*)p; p += 1024 * 4;
  float* coef2 = (float*)p; p += 512 * 4;

  prep_weights<<<3072, 256, 0, stream>>>(Wf, Wcat, W3cat);
  gauss_kernel<<<16384, 256, 0, stream>>>(dist, G);
  init_atom<<<16384, 256, 0, stream>>>(emb, atom);

  for (int l = 0; l < NCONV; ++l) {
    hipMemsetAsync(bn1, 0, (1024 + 512) * 4, stream);  // bn1 then bn2 (adjacent)
    int Mrows = (l == 0) ? NA : NB * NA;
    const float* Amat = (l == 0) ? emb : atom;
    float* Hl = (l == 0) ? H0 : H;
    gemm_f32<<<dim3(8, Mrows / 128), 256, 0, stream>>>(Amat, Wcat + (size_t)l * HA * 1024, Hl, Mrows);
    pass_a<<<dim3(NA / 8, NB), 256, 0, stream>>>(Hl, G, adj, W3cat + l * NF * 512, bn1, l > 0);
    finalize1<<<1, 512, 0, stream>>>(bn1, gh + l * 512, bh + l * 512, coef1);
    pass_b<<<dim3(NA / 8, NB), 256, 0, stream>>>(Hl, G, adj, W3cat + l * NF * 512, coef1, nbr, bn2, l > 0);
    finalize2<<<1, 256, 0, stream>>>(bn2, go + l * 256, bo + l * 256, coef2);
    pass_c<<<16384, 256, 0, stream>>>(atom, nbr, coef2);
  }
  epilogue<<<NB, 256, 0, stream>>>(atom, Wc, bc, out);
}

// Round 5
// 905.288 us; speedup vs baseline: 1.0466x; 1.0466x over previous
//
#include <hip/hip_runtime.h>
#include <math.h>

#define NB 64
#define NA 256
#define NM 16
#define HA 256
#define NF 16
#define NCONV 3
#define NCLS 6
#define EPSB 1e-5f

// ---------------- prep: pack weights ----------------
__global__ void prep_weights(const float* __restrict__ Wf,
                             float* __restrict__ Wcat, float* __restrict__ W3cat) {
  int i = blockIdx.x * 256 + threadIdx.x;
  const int TOT1 = NCONV * HA * 1024;
  if (i < TOT1) {
    int l = i / (HA * 1024);
    int r = i - l * (HA * 1024);
    int k = r >> 10, o = r & 1023;
    int row = (o < 512) ? k : (HA + k);
    int col = (o < 512) ? o : (o - 512);
    Wcat[i] = Wf[(l * 528 + row) * 512 + col];
  }
  const int TOT2 = NCONV * NF * 512;
  if (i < TOT2) {
    int l = i / (NF * 512);
    int r = i - l * (NF * 512);
    int k = r >> 9, o = r & 511;
    W3cat[i] = Wf[(l * 528 + 512 + k) * 512 + o];
  }
}

// Gaussian expansion table G[b,n,m,f] = exp(-(d - 0.2 f)^2 / 0.04)
__global__ void gauss_kernel(const float* __restrict__ dist, float* __restrict__ G) {
  int i = blockIdx.x * 256 + threadIdx.x;  // NB*NA*NM*NF exact
  int r = i >> 4, f = i & 15;
  float d = dist[r];
  float x = d - 0.2f * (float)f;
  G[i] = __expf(-x * x * 25.0f);
}

__global__ void init_atom(const float* __restrict__ emb, float* __restrict__ atom) {
  int i = blockIdx.x * 256 + threadIdx.x;  // NB*NA*HA exact
  atom[i] = emb[i & (NA * HA - 1)];
}

// ---------------- GEMM: A[Mrows][256] @ Bmat[256][1024] -> C[Mrows][1024], f32 ----------------
__global__ __launch_bounds__(256) void gemm_f32(const float* __restrict__ Amat,
                                                const float* __restrict__ Bmat,
                                                float* __restrict__ Cmat, int Mrows) {
  __shared__ float As[16][136];
  __shared__ float Bs[16][128];
  int t = threadIdx.x;
  int tx = t & 15, ty = t >> 4;
  int rowBase = blockIdx.y * 128;
  int colBase = blockIdx.x * 128;
  float acc[8][8];
#pragma unroll
  for (int i = 0; i < 8; ++i)
#pragma unroll
    for (int j = 0; j < 8; ++j) acc[i][j] = 0.f;

  for (int k0 = 0; k0 < HA; k0 += 16) {
#pragma unroll
    for (int cc = 0; cc < 2; ++cc) {
      int c = t + cc * 256;
      int row = c >> 2;
      int koff = (c & 3) << 2;
      float4 av = *(const float4*)&Amat[(rowBase + row) * HA + k0 + koff];
      As[koff + 0][row] = av.x; As[koff + 1][row] = av.y;
      As[koff + 2][row] = av.z; As[koff + 3][row] = av.w;
    }
#pragma unroll
    for (int cc = 0; cc < 2; ++cc) {
      int c = t + cc * 256;
      int k = c >> 5;
      int col = (c & 31) << 2;
      *(float4*)&Bs[k][col] = *(const float4*)&Bmat[(k0 + k) * 1024 + colBase + col];
    }
    __syncthreads();
#pragma unroll
    for (int k = 0; k < 16; ++k) {
      float a[8], bfr[8];
      *(float4*)&a[0] = *(const float4*)&As[k][ty * 8];
      *(float4*)&a[4] = *(const float4*)&As[k][ty * 8 + 4];
      *(float4*)&bfr[0] = *(const float4*)&Bs[k][tx * 4];
      *(float4*)&bfr[4] = *(const float4*)&Bs[k][64 + tx * 4];
#pragma unroll
      for (int i = 0; i < 8; ++i)
#pragma unroll
        for (int j = 0; j < 8; ++j) acc[i][j] += a[i] * bfr[j];
    }
    __syncthreads();
  }
#pragma unroll
  for (int i = 0; i < 8; ++i) {
    int r = rowBase + ty * 8 + i;
    float4 v0 = make_float4(acc[i][0], acc[i][1], acc[i][2], acc[i][3]);
    float4 v1 = make_float4(acc[i][4], acc[i][5], acc[i][6], acc[i][7]);
    *(float4*)&Cmat[r * 1024 + colBase + tx * 4] = v0;
    *(float4*)&Cmat[r * 1024 + colBase + 64 + tx * 4] = v1;
  }
}

// ---------------- XCD-swizzled block decode ----------------
// wg in [0,2048): x = wg&7 (XCD under round-robin), b = (wg>>8)*8 + x, ng = (wg>>3)&31
__device__ __forceinline__ void decode_wg(int wg, int& b, int& n0) {
  int x = wg & 7;
  int t2 = wg >> 3;
  int ng = t2 & 31;
  int bhi = t2 >> 5;
  b = bhi * 8 + x;
  n0 = ng * 8;
}

// ---------------- pass A: assemble z rows, accumulate BN1 stats ----------------
__global__ __launch_bounds__(256) void pass_a(const float* __restrict__ H,
                                              const float* __restrict__ G,
                                              const int* __restrict__ adj,
                                              const float* __restrict__ W3,
                                              float* __restrict__ bn1, int batched) {
  __shared__ float gg[8][NM][NF];
  __shared__ int ji[8][NM];
  int t = threadIdx.x;
  int b, n0;
  decode_wg(blockIdx.x, b, n0);
  {
    const float4* gs = (const float4*)&G[(size_t)(b * NA + n0) * (NM * NF)];
    float4* gd = (float4*)&gg[0][0][0];
    gd[t] = gs[t];
    gd[256 + t] = gs[256 + t];
    if (t < 128) ((int*)&ji[0][0])[t] = adj[(b * NA + n0) * NM + t];
  }
  float w3a[NF], w3b[NF];
#pragma unroll
  for (int k = 0; k < NF; ++k) {
    w3a[k] = W3[k * 512 + t];
    w3b[k] = W3[k * 512 + 256 + t];
  }
  __syncthreads();
  int hbase = batched ? b * NA : 0;
  float s1a = 0.f, s2a = 0.f, s1b = 0.f, s2b = 0.f;
  for (int nn = 0; nn < 8; ++nn) {
    int n = n0 + nn;
    const float* hself = &H[(size_t)(hbase + n) * 1024];
    float x1a = hself[t];
    float x1b = hself[256 + t];
    float ya[NM], yb[NM];
#pragma unroll
    for (int m = 0; m < NM; ++m) {
      const float* hr = &H[(size_t)(hbase + ji[nn][m]) * 1024 + 512];
      ya[m] = hr[t];
      yb[m] = hr[256 + t];
    }
#pragma unroll
    for (int m = 0; m < NM; ++m) {
      float ga = 0.f, gb = 0.f;
#pragma unroll
      for (int k = 0; k < NF; ++k) {
        float g = gg[nn][m][k];
        ga = fmaf(g, w3a[k], ga);
        gb = fmaf(g, w3b[k], gb);
      }
      float za = x1a + ya[m] + ga;
      float zb = x1b + yb[m] + gb;
      s1a += za; s2a = fmaf(za, za, s2a);
      s1b += zb; s2b = fmaf(zb, zb, s2b);
    }
  }
  atomicAdd(&bn1[t], s1a);
  atomicAdd(&bn1[256 + t], s1b);
  atomicAdd(&bn1[512 + t], s2a);
  atomicAdd(&bn1[768 + t], s2b);
}

__global__ void finalize1(const float* __restrict__ bn1, const float* __restrict__ g,
                          const float* __restrict__ beta, float* __restrict__ coef) {
  int t = threadIdx.x;  // 512
  const float inv = 1.0f / (float)(NB * NA * NM);
  float mu = bn1[t] * inv;
  float var = bn1[512 + t] * inv - mu * mu;
  float sc = g[t] * rsqrtf(var + EPSB);
  coef[t] = sc;
  coef[512 + t] = beta[t] - mu * sc;
}

// ---------------- pass B: recompute z, BN1+sigmoid*relu, sum over m, BN2 stats ----------------
__global__ __launch_bounds__(256) void pass_b(const float* __restrict__ H,
                                              const float* __restrict__ G,
                                              const int* __restrict__ adj,
                                              const float* __restrict__ W3,
                                              const float* __restrict__ coef,
                                              float* __restrict__ nbr,
                                              float* __restrict__ bn2, int batched) {
  __shared__ float gg[8][NM][NF];
  __shared__ int ji[8][NM];
  int t = threadIdx.x;
  int b, n0;
  decode_wg(blockIdx.x, b, n0);
  {
    const float4* gs = (const float4*)&G[(size_t)(b * NA + n0) * (NM * NF)];
    float4* gd = (float4*)&gg[0][0][0];
    gd[t] = gs[t];
    gd[256 + t] = gs[256 + t];
    if (t < 128) ((int*)&ji[0][0])[t] = adj[(b * NA + n0) * NM + t];
  }
  float w3a[NF], w3b[NF];
#pragma unroll
  for (int k = 0; k < NF; ++k) {
    w3a[k] = W3[k * 512 + t];
    w3b[k] = W3[k * 512 + 256 + t];
  }
  float scf = coef[t], shf = coef[512 + t];
  float scc = coef[256 + t], shc = coef[768 + t];
  __syncthreads();
  int hbase = batched ? b * NA : 0;
  float sB1 = 0.f, sB2 = 0.f;
  for (int nn = 0; nn < 8; ++nn) {
    int n = n0 + nn;
    const float* hself = &H[(size_t)(hbase + n) * 1024];
    float x1a = hself[t];
    float x1b = hself[256 + t];
    float ya[NM], yb[NM];
#pragma unroll
    for (int m = 0; m < NM; ++m) {
      const float* hr = &H[(size_t)(hbase + ji[nn][m]) * 1024 + 512];
      ya[m] = hr[t];
      yb[m] = hr[256 + t];
    }
    float acc = 0.f;
#pragma unroll
    for (int m = 0; m < NM; ++m) {
      float ga = 0.f, gb = 0.f;
#pragma unroll
      for (int k = 0; k < NF; ++k) {
        float g = gg[nn][m][k];
        ga = fmaf(g, w3a[k], ga);
        gb = fmaf(g, w3b[k], gb);
      }
      float za = x1a + ya[m] + ga;
      float zb = x1b + yb[m] + gb;
      float yf = fmaf(za, scf, shf);
      float yc = fmaf(zb, scc, shc);
      float sig = 1.0f / (1.0f + __expf(-yf));
      float core = fmaxf(yc, 0.f);
      acc = fmaf(sig, core, acc);
    }
    nbr[(size_t)(b * NA + n) * HA + t] = acc;
    sB1 += acc;
    sB2 = fmaf(acc, acc, sB2);
  }
  atomicAdd(&bn2[t], sB1);
  atomicAdd(&bn2[256 + t], sB2);
}

__global__ void finalize2(const float* __restrict__ bn2, const float* __restrict__ g,
                          const float* __restrict__ beta, float* __restrict__ coef2) {
  int t = threadIdx.x;  // 256
  const float inv = 1.0f / (float)(NB * NA);
  float mu = bn2[t] * inv;
  float var = bn2[256 + t] * inv - mu * mu;
  float sc = g[t] * rsqrtf(var + EPSB);
  coef2[t] = sc;
  coef2[256 + t] = beta[t] - mu * sc;
}

__global__ void pass_c(float4* __restrict__ atom, const float4* __restrict__ nbr,
                       const float* __restrict__ coef2) {
  int i = blockIdx.x * 256 + threadIdx.x;  // NB*NA*HA/4 exact
  int o = (i & 63) * 4;
  float4 a = atom[i];
  float4 nv = nbr[i];
  a.x = fmaxf(a.x + fmaf(nv.x, coef2[o + 0], coef2[256 + o + 0]), 0.f);
  a.y = fmaxf(a.y + fmaf(nv.y, coef2[o + 1], coef2[256 + o + 1]), 0.f);
  a.z = fmaxf(a.z + fmaf(nv.z, coef2[o + 2], coef2[256 + o + 2]), 0.f);
  a.w = fmaxf(a.w + fmaf(nv.w, coef2[o + 3], coef2[256 + o + 3]), 0.f);
  atom[i] = a;
}

// ---------------- epilogue: pool over n, classifier, softmax ----------------
__global__ __launch_bounds__(256) void epilogue(const float* __restrict__ atom,
                                                const float* __restrict__ Wc,
                                                const float* __restrict__ bc,
                                                float* __restrict__ out) {
  __shared__ float pooled[HA];
  __shared__ float lg[NCLS];
  int b = blockIdx.x, t = threadIdx.x;
  float s = 0.f;
  for (int n = 0; n < NA; ++n) s += atom[(size_t)(b * NA + n) * HA + t];
  pooled[t] = s * (1.0f / (float)NA);
  __syncthreads();
  if (t < NCLS) {
    float a = bc[t];
    for (int o = 0; o < HA; ++o) a += pooled[o] * Wc[o * NCLS + t];
    lg[t] = a;
  }
  __syncthreads();
  if (t == 0) {
    float mx = lg[0];
    for (int c = 1; c < NCLS; ++c) mx = fmaxf(mx, lg[c]);
    float e[NCLS], den = 0.f;
    for (int c = 0; c < NCLS; ++c) { e[c] = __expf(lg[c] - mx); den += e[c]; }
    for (int c = 0; c < NCLS; ++c) out[b * NCLS + c] = e[c] / den;
  }
}

extern "C" void kernel_launch(void* const* d_in, const int* in_sizes, int n_in,
                              void* d_out, int out_size, void* d_ws, size_t ws_size,
                              hipStream_t stream) {
  const float* dist = (const float*)d_in[0];
  const int* adj = (const int*)d_in[1];
  const float* emb = (const float*)d_in[2];
  const float* Wf = (const float*)d_in[3];
  const float* gh = (const float*)d_in[5];
  const float* bh = (const float*)d_in[6];
  const float* go = (const float*)d_in[7];
  const float* bo = (const float*)d_in[8];
  const float* Wc = (const float*)d_in[9];
  const float* bc = (const float*)d_in[10];
  float* out = (float*)d_out;

  char* p = (char*)d_ws;
  float* G = (float*)p;     p += (size_t)NB * NA * NM * NF * 4;
  float* H = (float*)p;     p += (size_t)NB * NA * 1024 * 4;
  float* H0 = (float*)p;    p += (size_t)NA * 1024 * 4;
  float* atom = (float*)p;  p += (size_t)NB * NA * HA * 4;
  float* nbr = (float*)p;   p += (size_t)NB * NA * HA * 4;
  float* Wcat = (float*)p;  p += (size_t)NCONV * HA * 1024 * 4;
  float* W3cat = (float*)p; p += (size_t)NCONV * NF * 512 * 4;
  float* bn1 = (float*)p;   p += 1024 * 4;
  float* bn2 = (float*)p;   p += 512 * 4;
  float* coef1 = (float*)p; p += 1024 * 4;
  float* coef2 = (float*)p; p += 512 * 4;

  prep_weights<<<3072, 256, 0, stream>>>(Wf, Wcat, W3cat);
  gauss_kernel<<<16384, 256, 0, stream>>>(dist, G);
  init_atom<<<16384, 256, 0, stream>>>(emb, atom);

  for (int l = 0; l < NCONV; ++l) {
    hipMemsetAsync(bn1, 0, (1024 + 512) * 4, stream);
    int Mrows = (l == 0) ? NA : NB * NA;
    const float* Amat = (l == 0) ? emb : atom;
    float* Hl = (l == 0) ? H0 : H;
    gemm_f32<<<dim3(8, Mrows / 128), 256, 0, stream>>>(Amat, Wcat + (size_t)l * HA * 1024, Hl, Mrows);
    pass_a<<<2048, 256, 0, stream>>>(Hl, G, adj, W3cat + l * NF * 512, bn1, l > 0);
    finalize1<<<1, 512, 0, stream>>>(bn1, gh + l * 512, bh + l * 512, coef1);
    pass_b<<<2048, 256, 0, stream>>>(Hl, G, adj, W3cat + l * NF * 512, coef1, nbr, bn2, l > 0);
    finalize2<<<1, 256, 0, stream>>>(bn2, go + l * 256, bo + l * 256, coef2);
    pass_c<<<4096, 256, 0, stream>>>((float4*)atom, (const float4*)nbr, coef2);
  }
  epilogue<<<NB, 256, 0, stream>>>(atom, Wc, bc, out);
}

// Round 6
// 731.658 us; speedup vs baseline: 1.2950x; 1.2373x over previous
//
#include <hip/hip_runtime.h>
#include <math.h>

#define NB 64
#define NA 256
#define NM 16
#define HA 256
#define NF 16
#define NCONV 3
#define NCLS 6
#define EPSB 1e-5f

typedef __attribute__((ext_vector_type(8))) short short8v;   // 8 bf16 (4 VGPR)
typedef __attribute__((ext_vector_type(4))) float f32x4;

__device__ __forceinline__ short f2bf(float x) {
  union { float f; unsigned u; } v; v.f = x;
  unsigned r = v.u + 0x7fff + ((v.u >> 16) & 1);  // RTNE
  return (short)(r >> 16);
}

// ---------------- prep: WT bf16 [l][1024][256] (o-major, k contiguous) + W3cat f32 ----------------
__global__ void prep_weights(const float* __restrict__ Wf,
                             short* __restrict__ WT, float* __restrict__ W3cat) {
  int i = blockIdx.x * 256 + threadIdx.x;
  const int TOT1 = NCONV * 1024 * 256;  // 786432 = 3072*256 exact
  if (i < TOT1) {
    int l = i / (1024 * 256);
    int r = i - l * (1024 * 256);
    int o = r >> 8, k = r & 255;
    float w = (o < 512) ? Wf[(l * 528 + k) * 512 + o]
                        : Wf[(l * 528 + 256 + k) * 512 + (o - 512)];
    WT[i] = f2bf(w);
  }
  const int TOT2 = NCONV * NF * 512;
  if (i < TOT2) {
    int l = i / (NF * 512);
    int r = i - l * (NF * 512);
    int k = r >> 9, o = r & 511;
    W3cat[i] = Wf[(l * 528 + 512 + k) * 512 + o];
  }
}

// Gaussian expansion table G[b,n,m,f] = exp(-(d - 0.2 f)^2 / 0.04)
__global__ void gauss_kernel(const float* __restrict__ dist, float* __restrict__ G) {
  int i = blockIdx.x * 256 + threadIdx.x;
  int r = i >> 4, f = i & 15;
  float d = dist[r];
  float x = d - 0.2f * (float)f;
  G[i] = __expf(-x * x * 25.0f);
}

__global__ void init_atom(const float* __restrict__ emb, float* __restrict__ atom) {
  int i = blockIdx.x * 256 + threadIdx.x;
  atom[i] = emb[i & (NA * HA - 1)];
}

__global__ void emb_bf(const float* __restrict__ emb, short* __restrict__ ebf) {
  int i = blockIdx.x * 256 + threadIdx.x;  // NA*HA exact
  ebf[i] = f2bf(emb[i]);
}

// ---------------- MFMA GEMM: C[M][1024] f32 = Abf[M][256] @ WT^T, bf16 in / f32 acc ----------------
// 128x128 tile, 4 waves (2x2), wave = 64x64 = 4x4 fragments of 16x16; BK=64, K=256 -> 4 iters.
__global__ __launch_bounds__(256) void gemm_mfma(const short* __restrict__ Abf,
                                                 const short* __restrict__ WT,
                                                 float* __restrict__ C, int Mrows) {
  __shared__ short As[128][72];  // rows padded 64->72 (144B, 16B-aligned, bank-spread)
  __shared__ short Bs[128][72];  // Bs[col][k]
  int t = threadIdx.x;
  int wave = t >> 6, lane = t & 63;
  int wr = wave >> 1, wc = wave & 1;
  int l16 = lane & 15, lhi = lane >> 4;

  int wg = blockIdx.x;
  int nRowBlocks = Mrows >> 7;
  int rowBlock, colBlock;
  if (nRowBlocks >= 8) {
    // keep the 8 col-blocks of one row-block on one XCD (wg%8 fixed) for A-tile L2 reuse
    rowBlock = (wg & 7) + ((wg >> 6) << 3);
    colBlock = (wg >> 3) & 7;
  } else {
    rowBlock = wg % nRowBlocks;
    colBlock = wg / nRowBlocks;
  }
  int rowBase = rowBlock << 7, colBase = colBlock << 7;

  f32x4 acc[4][4];
#pragma unroll
  for (int i = 0; i < 4; ++i)
#pragma unroll
    for (int j = 0; j < 4; ++j) acc[i][j] = (f32x4)(0.f);

  for (int k0 = 0; k0 < 256; k0 += 64) {
    // stage: 128x64 bf16 = 1024 16B-chunks per matrix, 4 chunks/thread
#pragma unroll
    for (int cc = 0; cc < 4; ++cc) {
      int c = t + cc * 256;
      int row = c >> 3, ko = (c & 7) << 3;
      *(int4*)&As[row][ko] = *(const int4*)&Abf[(size_t)(rowBase + row) * 256 + k0 + ko];
      *(int4*)&Bs[row][ko] = *(const int4*)&WT[(size_t)(colBase + row) * 256 + k0 + ko];
    }
    __syncthreads();
#pragma unroll
    for (int ks = 0; ks < 2; ++ks) {
      int kk = ks * 32 + lhi * 8;
      short8v a[4], b[4];
#pragma unroll
      for (int f = 0; f < 4; ++f) {
        a[f] = *(const short8v*)&As[wr * 64 + f * 16 + l16][kk];
        b[f] = *(const short8v*)&Bs[wc * 64 + f * 16 + l16][kk];
      }
#pragma unroll
      for (int i = 0; i < 4; ++i)
#pragma unroll
        for (int j = 0; j < 4; ++j)
          acc[i][j] = __builtin_amdgcn_mfma_f32_16x16x32_bf16(a[i], b[j], acc[i][j], 0, 0, 0);
    }
    __syncthreads();
  }
  // C/D layout: col = lane&15, row = (lane>>4)*4 + reg
#pragma unroll
  for (int i = 0; i < 4; ++i) {
#pragma unroll
    for (int j = 0; j < 4; ++j) {
      int col = colBase + wc * 64 + j * 16 + l16;
      int row0 = rowBase + wr * 64 + i * 16 + lhi * 4;
#pragma unroll
      for (int r = 0; r < 4; ++r)
        C[(size_t)(row0 + r) * 1024 + col] = acc[i][j][r];
    }
  }
}

// ---------------- XCD-swizzled block decode for passes ----------------
__device__ __forceinline__ void decode_wg(int wg, int& b, int& n0) {
  int x = wg & 7;
  int t2 = wg >> 3;
  int ng = t2 & 31;
  int bhi = t2 >> 5;
  b = bhi * 8 + x;
  n0 = ng * 8;
}

// ---------------- pass A: assemble z rows, accumulate BN1 stats ----------------
__global__ __launch_bounds__(256) void pass_a(const float* __restrict__ H,
                                              const float* __restrict__ G,
                                              const int* __restrict__ adj,
                                              const float* __restrict__ W3,
                                              float* __restrict__ bn1, int batched) {
  __shared__ float gg[8][NM][NF];
  __shared__ int ji[8][NM];
  int t = threadIdx.x;
  int b, n0;
  decode_wg(blockIdx.x, b, n0);
  {
    const float4* gs = (const float4*)&G[(size_t)(b * NA + n0) * (NM * NF)];
    float4* gd = (float4*)&gg[0][0][0];
    gd[t] = gs[t];
    gd[256 + t] = gs[256 + t];
    if (t < 128) ((int*)&ji[0][0])[t] = adj[(b * NA + n0) * NM + t];
  }
  float w3a[NF], w3b[NF];
#pragma unroll
  for (int k = 0; k < NF; ++k) {
    w3a[k] = W3[k * 512 + t];
    w3b[k] = W3[k * 512 + 256 + t];
  }
  __syncthreads();
  int hbase = batched ? b * NA : 0;
  float s1a = 0.f, s2a = 0.f, s1b = 0.f, s2b = 0.f;
  for (int nn = 0; nn < 8; ++nn) {
    int n = n0 + nn;
    const float* hself = &H[(size_t)(hbase + n) * 1024];
    float x1a = hself[t];
    float x1b = hself[256 + t];
    float ya[NM], yb[NM];
#pragma unroll
    for (int m = 0; m < NM; ++m) {
      const float* hr = &H[(size_t)(hbase + ji[nn][m]) * 1024 + 512];
      ya[m] = hr[t];
      yb[m] = hr[256 + t];
    }
#pragma unroll
    for (int m = 0; m < NM; ++m) {
      float ga = 0.f, gb = 0.f;
#pragma unroll
      for (int k = 0; k < NF; ++k) {
        float g = gg[nn][m][k];
        ga = fmaf(g, w3a[k], ga);
        gb = fmaf(g, w3b[k], gb);
      }
      float za = x1a + ya[m] + ga;
      float zb = x1b + yb[m] + gb;
      s1a += za; s2a = fmaf(za, za, s2a);
      s1b += zb; s2b = fmaf(zb, zb, s2b);
    }
  }
  atomicAdd(&bn1[t], s1a);
  atomicAdd(&bn1[256 + t], s1b);
  atomicAdd(&bn1[512 + t], s2a);
  atomicAdd(&bn1[768 + t], s2b);
}

__global__ void finalize1(const float* __restrict__ bn1, const float* __restrict__ g,
                          const float* __restrict__ beta, float* __restrict__ coef) {
  int t = threadIdx.x;  // 512
  const float inv = 1.0f / (float)(NB * NA * NM);
  float mu = bn1[t] * inv;
  float var = bn1[512 + t] * inv - mu * mu;
  float sc = g[t] * rsqrtf(var + EPSB);
  coef[t] = sc;
  coef[512 + t] = beta[t] - mu * sc;
}

// ---------------- pass B ----------------
__global__ __launch_bounds__(256) void pass_b(const float* __restrict__ H,
                                              const float* __restrict__ G,
                                              const int* __restrict__ adj,
                                              const float* __restrict__ W3,
                                              const float* __restrict__ coef,
                                              float* __restrict__ nbr,
                                              float* __restrict__ bn2, int batched) {
  __shared__ float gg[8][NM][NF];
  __shared__ int ji[8][NM];
  int t = threadIdx.x;
  int b, n0;
  decode_wg(blockIdx.x, b, n0);
  {
    const float4* gs = (const float4*)&G[(size_t)(b * NA + n0) * (NM * NF)];
    float4* gd = (float4*)&gg[0][0][0];
    gd[t] = gs[t];
    gd[256 + t] = gs[256 + t];
    if (t < 128) ((int*)&ji[0][0])[t] = adj[(b * NA + n0) * NM + t];
  }
  float w3a[NF], w3b[NF];
#pragma unroll
  for (int k = 0; k < NF; ++k) {
    w3a[k] = W3[k * 512 + t];
    w3b[k] = W3[k * 512 + 256 + t];
  }
  float scf = coef[t], shf = coef[512 + t];
  float scc = coef[256 + t], shc = coef[768 + t];
  __syncthreads();
  int hbase = batched ? b * NA : 0;
  float sB1 = 0.f, sB2 = 0.f;
  for (int nn = 0; nn < 8; ++nn) {
    int n = n0 + nn;
    const float* hself = &H[(size_t)(hbase + n) * 1024];
    float x1a = hself[t];
    float x1b = hself[256 + t];
    float ya[NM], yb[NM];
#pragma unroll
    for (int m = 0; m < NM; ++m) {
      const float* hr = &H[(size_t)(hbase + ji[nn][m]) * 1024 + 512];
      ya[m] = hr[t];
      yb[m] = hr[256 + t];
    }
    float acc = 0.f;
#pragma unroll
    for (int m = 0; m < NM; ++m) {
      float ga = 0.f, gb = 0.f;
#pragma unroll
      for (int k = 0; k < NF; ++k) {
        float g = gg[nn][m][k];
        ga = fmaf(g, w3a[k], ga);
        gb = fmaf(g, w3b[k], gb);
      }
      float za = x1a + ya[m] + ga;
      float zb = x1b + yb[m] + gb;
      float yf = fmaf(za, scf, shf);
      float yc = fmaf(zb, scc, shc);
      float sig = 1.0f / (1.0f + __expf(-yf));
      float core = fmaxf(yc, 0.f);
      acc = fmaf(sig, core, acc);
    }
    nbr[(size_t)(b * NA + n) * HA + t] = acc;
    sB1 += acc;
    sB2 = fmaf(acc, acc, sB2);
  }
  atomicAdd(&bn2[t], sB1);
  atomicAdd(&bn2[256 + t], sB2);
}

__global__ void finalize2(const float* __restrict__ bn2, const float* __restrict__ g,
                          const float* __restrict__ beta, float* __restrict__ coef2) {
  int t = threadIdx.x;  // 256
  const float inv = 1.0f / (float)(NB * NA);
  float mu = bn2[t] * inv;
  float var = bn2[256 + t] * inv - mu * mu;
  float sc = g[t] * rsqrtf(var + EPSB);
  coef2[t] = sc;
  coef2[256 + t] = beta[t] - mu * sc;
}

// pass_c: atom = relu(atom + nbr*sc + sh); also emit bf16 copy for next layer's GEMM A
__global__ void pass_c(float4* __restrict__ atom, const float4* __restrict__ nbr,
                       const float* __restrict__ coef2, short* __restrict__ abf) {
  int i = blockIdx.x * 256 + threadIdx.x;  // NB*NA*HA/4 exact
  int o = (i & 63) * 4;
  float4 a = atom[i];
  float4 nv = nbr[i];
  a.x = fmaxf(a.x + fmaf(nv.x, coef2[o + 0], coef2[256 + o + 0]), 0.f);
  a.y = fmaxf(a.y + fmaf(nv.y, coef2[o + 1], coef2[256 + o + 1]), 0.f);
  a.z = fmaxf(a.z + fmaf(nv.z, coef2[o + 2], coef2[256 + o + 2]), 0.f);
  a.w = fmaxf(a.w + fmaf(nv.w, coef2[o + 3], coef2[256 + o + 3]), 0.f);
  atom[i] = a;
  short4 s;
  s.x = f2bf(a.x); s.y = f2bf(a.y); s.z = f2bf(a.z); s.w = f2bf(a.w);
  *(short4*)&abf[(size_t)i * 4] = s;
}

// ---------------- epilogue ----------------
__global__ __launch_bounds__(256) void epilogue(const float* __restrict__ atom,
                                                const float* __restrict__ Wc,
                                                const float* __restrict__ bc,
                                                float* __restrict__ out) {
  __shared__ float pooled[HA];
  __shared__ float lg[NCLS];
  int b = blockIdx.x, t = threadIdx.x;
  float s = 0.f;
  for (int n = 0; n < NA; ++n) s += atom[(size_t)(b * NA + n) * HA + t];
  pooled[t] = s * (1.0f / (float)NA);
  __syncthreads();
  if (t < NCLS) {
    float a = bc[t];
    for (int o = 0; o < HA; ++o) a += pooled[o] * Wc[o * NCLS + t];
    lg[t] = a;
  }
  __syncthreads();
  if (t == 0) {
    float mx = lg[0];
    for (int c = 1; c < NCLS; ++c) mx = fmaxf(mx, lg[c]);
    float e[NCLS], den = 0.f;
    for (int c = 0; c < NCLS; ++c) { e[c] = __expf(lg[c] - mx); den += e[c]; }
    for (int c = 0; c < NCLS; ++c) out[b * NCLS + c] = e[c] / den;
  }
}

extern "C" void kernel_launch(void* const* d_in, const int* in_sizes, int n_in,
                              void* d_out, int out_size, void* d_ws, size_t ws_size,
                              hipStream_t stream) {
  const float* dist = (const float*)d_in[0];
  const int* adj = (const int*)d_in[1];
  const float* emb = (const float*)d_in[2];
  const float* Wf = (const float*)d_in[3];
  const float* gh = (const float*)d_in[5];
  const float* bh = (const float*)d_in[6];
  const float* go = (const float*)d_in[7];
  const float* bo = (const float*)d_in[8];
  const float* Wc = (const float*)d_in[9];
  const float* bc = (const float*)d_in[10];
  float* out = (float*)d_out;

  char* p = (char*)d_ws;
  float* G = (float*)p;     p += (size_t)NB * NA * NM * NF * 4;   // 16 MB
  float* H = (float*)p;     p += (size_t)NB * NA * 1024 * 4;      // 64 MB
  float* H0 = (float*)p;    p += (size_t)NA * 1024 * 4;           // 1 MB
  float* atom = (float*)p;  p += (size_t)NB * NA * HA * 4;        // 16 MB
  float* nbr = (float*)p;   p += (size_t)NB * NA * HA * 4;        // 16 MB
  short* WT = (short*)p;    p += (size_t)NCONV * 1024 * 256 * 2;  // 1.5 MB
  short* Abf = (short*)p;   p += (size_t)NB * NA * 256 * 2;       // 8 MB
  short* Ebf = (short*)p;   p += (size_t)NA * 256 * 2;            // 128 KB
  float* W3cat = (float*)p; p += (size_t)NCONV * NF * 512 * 4;
  float* bn1 = (float*)p;   p += 1024 * 4;
  float* bn2 = (float*)p;   p += 512 * 4;
  float* coef1 = (float*)p; p += 1024 * 4;
  float* coef2 = (float*)p; p += 512 * 4;

  prep_weights<<<3072, 256, 0, stream>>>(Wf, WT, W3cat);
  gauss_kernel<<<16384, 256, 0, stream>>>(dist, G);
  init_atom<<<16384, 256, 0, stream>>>(emb, atom);
  emb_bf<<<256, 256, 0, stream>>>(emb, Ebf);

  for (int l = 0; l < NCONV; ++l) {
    hipMemsetAsync(bn1, 0, (1024 + 512) * 4, stream);
    int Mrows = (l == 0) ? NA : NB * NA;
    const short* Amat = (l == 0) ? Ebf : Abf;
    float* Hl = (l == 0) ? H0 : H;
    gemm_mfma<<<(Mrows / 128) * 8, 256, 0, stream>>>(Amat, WT + (size_t)l * 1024 * 256, Hl, Mrows);
    pass_a<<<2048, 256, 0, stream>>>(Hl, G, adj, W3cat + l * NF * 512, bn1, l > 0);
    finalize1<<<1, 512, 0, stream>>>(bn1, gh + l * 512, bh + l * 512, coef1);
    pass_b<<<2048, 256, 0, stream>>>(Hl, G, adj, W3cat + l * NF * 512, coef1, nbr, bn2, l > 0);
    finalize2<<<1, 256, 0, stream>>>(bn2, go + l * 256, bo + l * 256, coef2);
    pass_c<<<4096, 256, 0, stream>>>((float4*)atom, (const float4*)nbr, coef2, Abf);
  }
  epilogue<<<NB, 256, 0, stream>>>(atom, Wc, bc, out);
}

// Round 7
// 571.910 us; speedup vs baseline: 1.6567x; 1.2793x over previous
//
#include <hip/hip_runtime.h>
#include <math.h>

#define NB 64
#define NA 256
#define NM 16
#define HA 256
#define NF 16
#define NCONV 3
#define NCLS 6
#define EPSB 1e-5f

typedef __attribute__((ext_vector_type(8))) short short8v;   // 8 bf16 (4 VGPR)
typedef __attribute__((ext_vector_type(4))) float f32x4;

__device__ __forceinline__ short f2bf(float x) {
  union { float f; unsigned u; } v; v.f = x;
  unsigned r = v.u + 0x7fff + ((v.u >> 16) & 1);  // RTNE
  return (short)(r >> 16);
}

// ---------------- prep: WT bf16 [l][1024][256] + W3bf bf16 [l][512 o][16 k] ----------------
__global__ void prep_weights(const float* __restrict__ Wf,
                             short* __restrict__ WT, short* __restrict__ W3bf) {
  int i = blockIdx.x * 256 + threadIdx.x;
  const int TOT1 = NCONV * 1024 * 256;
  if (i < TOT1) {
    int l = i / (1024 * 256);
    int r = i - l * (1024 * 256);
    int o = r >> 8, k = r & 255;
    float w = (o < 512) ? Wf[(l * 528 + k) * 512 + o]
                        : Wf[(l * 528 + 256 + k) * 512 + (o - 512)];
    WT[i] = f2bf(w);
  }
  const int TOT2 = NCONV * 512 * NF;  // 24576, [l][o][k]
  if (i < TOT2) {
    int l = i / (512 * NF);
    int r = i - l * (512 * NF);
    int o = r >> 4, k = r & 15;
    W3bf[i] = f2bf(Wf[(l * 528 + 512 + k) * 512 + o]);
  }
}

// Gaussian expansion, bf16 out: Gbf[b,n,m,k] = bf16(exp(-(d - 0.2k)^2/0.04))
__global__ void gauss_kernel(const float* __restrict__ dist, short* __restrict__ Gbf) {
  int i = blockIdx.x * 256 + threadIdx.x;
  int r = i >> 4, f = i & 15;
  float d = dist[r];
  float x = d - 0.2f * (float)f;
  Gbf[i] = f2bf(__expf(-x * x * 25.0f));
}

__global__ void init_atom(const float* __restrict__ emb, float* __restrict__ atom) {
  int i = blockIdx.x * 256 + threadIdx.x;
  atom[i] = emb[i & (NA * HA - 1)];
}

__global__ void emb_bf(const float* __restrict__ emb, short* __restrict__ ebf) {
  int i = blockIdx.x * 256 + threadIdx.x;
  ebf[i] = f2bf(emb[i]);
}

// ---------------- MFMA GEMM: C[M][1024] f32 = Abf[M][256] @ WT^T ----------------
__global__ __launch_bounds__(256) void gemm_mfma(const short* __restrict__ Abf,
                                                 const short* __restrict__ WT,
                                                 float* __restrict__ C, int Mrows) {
  __shared__ short As[128][72];
  __shared__ short Bs[128][72];
  int t = threadIdx.x;
  int wave = t >> 6, lane = t & 63;
  int wr = wave >> 1, wc = wave & 1;
  int l16 = lane & 15, lhi = lane >> 4;

  int wg = blockIdx.x;
  int nRowBlocks = Mrows >> 7;
  int rowBlock, colBlock;
  if (nRowBlocks >= 8) {
    rowBlock = (wg & 7) + ((wg >> 6) << 3);
    colBlock = (wg >> 3) & 7;
  } else {
    rowBlock = wg % nRowBlocks;
    colBlock = wg / nRowBlocks;
  }
  int rowBase = rowBlock << 7, colBase = colBlock << 7;

  f32x4 acc[4][4];
#pragma unroll
  for (int i = 0; i < 4; ++i)
#pragma unroll
    for (int j = 0; j < 4; ++j) acc[i][j] = (f32x4)(0.f);

  for (int k0 = 0; k0 < 256; k0 += 64) {
#pragma unroll
    for (int cc = 0; cc < 4; ++cc) {
      int c = t + cc * 256;
      int row = c >> 3, ko = (c & 7) << 3;
      *(int4*)&As[row][ko] = *(const int4*)&Abf[(size_t)(rowBase + row) * 256 + k0 + ko];
      *(int4*)&Bs[row][ko] = *(const int4*)&WT[(size_t)(colBase + row) * 256 + k0 + ko];
    }
    __syncthreads();
#pragma unroll
    for (int ks = 0; ks < 2; ++ks) {
      int kk = ks * 32 + lhi * 8;
      short8v a[4], b[4];
#pragma unroll
      for (int f = 0; f < 4; ++f) {
        a[f] = *(const short8v*)&As[wr * 64 + f * 16 + l16][kk];
        b[f] = *(const short8v*)&Bs[wc * 64 + f * 16 + l16][kk];
      }
#pragma unroll
      for (int i = 0; i < 4; ++i)
#pragma unroll
        for (int j = 0; j < 4; ++j)
          acc[i][j] = __builtin_amdgcn_mfma_f32_16x16x32_bf16(a[i], b[j], acc[i][j], 0, 0, 0);
    }
    __syncthreads();
  }
#pragma unroll
  for (int i = 0; i < 4; ++i) {
#pragma unroll
    for (int j = 0; j < 4; ++j) {
      int col = colBase + wc * 64 + j * 16 + l16;
      int row0 = rowBase + wr * 64 + i * 16 + lhi * 4;
#pragma unroll
      for (int r = 0; r < 4; ++r)
        C[(size_t)(row0 + r) * 1024 + col] = acc[i][j][r];
    }
  }
}

// ---------------- XCD-swizzled block decode for passes ----------------
__device__ __forceinline__ void decode_wg(int wg, int& b, int& n0) {
  int x = wg & 7;
  int t2 = wg >> 3;
  int ng = t2 & 31;
  int bhi = t2 >> 5;
  b = bhi * 8 + x;
  n0 = ng * 8;
}

// ---------------- unified MFMA pass: PASS=0 -> BN1 stats; PASS=1 -> BN apply+sig*relu+m-sum ----
// Per block: 8 n's x 16 m's = 128 rows; z = (G @ W3)[row][o] + x1[n][o] + y[nbr(row)][o], o in [0,512)
// MFMA does G@W3 (K=16 zero-padded to 32); fragment layouts identical to gemm_mfma (verified).
template <int PASS>
__global__ __launch_bounds__(256, 2) void pass_mfma(const float* __restrict__ H,
                                                    const short* __restrict__ Gbf,
                                                    const int* __restrict__ adj,
                                                    const short* __restrict__ W3bf,
                                                    const float* __restrict__ coef,
                                                    float* __restrict__ nbr,
                                                    float* __restrict__ stats,
                                                    int batched) {
  __shared__ short Gb[128][40];    // [row=(nn,m)][k 0..31 zero-padded, +pad]
  __shared__ short W3t[512][40];   // [col o][k 0..31 zero-padded, +pad]
  __shared__ float x1s[8][512];    // self H rows
  __shared__ int jis[128];
  __shared__ float cf[1024];       // coef (pass_b)

  int t = threadIdx.x;
  int b, n0;
  decode_wg(blockIdx.x, b, n0);
  int hbase = batched ? b * NA : 0;

  // ---- stage ----
#pragma unroll
  for (int c = 0; c < 2; ++c) {  // W3t: 2 cols/thread
    int col = t * 2 + c;
    const int4* src = (const int4*)&W3bf[(size_t)col * 16];
    *(int4*)&W3t[col][0] = src[0];
    *(int4*)&W3t[col][8] = src[1];
    *(int4*)&W3t[col][16] = make_int4(0, 0, 0, 0);
    *(int4*)&W3t[col][24] = make_int4(0, 0, 0, 0);
  }
  if (t < 128) {  // G rows + adj
    const int4* src = (const int4*)&Gbf[((size_t)(b * NA + n0) * NM + t) * NF];
    *(int4*)&Gb[t][0] = src[0];
    *(int4*)&Gb[t][8] = src[1];
    *(int4*)&Gb[t][16] = make_int4(0, 0, 0, 0);
    *(int4*)&Gb[t][24] = make_int4(0, 0, 0, 0);
    jis[t] = adj[(b * NA + n0) * NM + t];
  }
  {  // x1s: 16 f32/thread
    int nn = t >> 5, c0 = (t & 31) * 16;
    const float4* src = (const float4*)&H[(size_t)(hbase + n0 + nn) * 1024 + c0];
    float4* dst = (float4*)&x1s[nn][c0];
    dst[0] = src[0]; dst[1] = src[1]; dst[2] = src[2]; dst[3] = src[3];
  }
  if (PASS == 1) {
    cf[t] = coef[t]; cf[256 + t] = coef[256 + t];
    cf[512 + t] = coef[512 + t]; cf[768 + t] = coef[768 + t];
  }
  __syncthreads();

  int lane = t & 63, wv = t >> 6;
  int l16 = lane & 15, lhi = lane >> 4;

  // b-frags + per-lane column indices (4 filter cols then 4 core cols)
  short8v bf[8];
  int oc[8];
#pragma unroll
  for (int j = 0; j < 8; ++j) {
    int col = wv * 64 + (j & 3) * 16 + l16 + ((j >= 4) ? 256 : 0);
    oc[j] = col;
    bf[j] = *(const short8v*)&W3t[col][lhi * 8];
  }

  float scf[4], shf[4], scc[4], shc[4];
  if (PASS == 1) {
#pragma unroll
    for (int p = 0; p < 4; ++p) {
      scf[p] = cf[oc[p]];       shf[p] = cf[512 + oc[p]];
      scc[p] = cf[oc[p + 4]];   shc[p] = cf[512 + oc[p + 4]];
    }
  }

  float s1f[4] = {0, 0, 0, 0}, s2f[4] = {0, 0, 0, 0};
  float s1c[4] = {0, 0, 0, 0}, s2c[4] = {0, 0, 0, 0};
  float sB1[4] = {0, 0, 0, 0}, sB2[4] = {0, 0, 0, 0};

  for (int h = 0; h < 2; ++h) {  // 4 n's per half -> acc[4][8]
    f32x4 acc[4][8];
#pragma unroll
    for (int f = 0; f < 4; ++f)
#pragma unroll
      for (int j = 0; j < 8; ++j) acc[f][j] = (f32x4)(0.f);
    short8v af[4];
#pragma unroll
    for (int f = 0; f < 4; ++f)
      af[f] = *(const short8v*)&Gb[(h * 4 + f) * 16 + l16][lhi * 8];
#pragma unroll
    for (int f = 0; f < 4; ++f)
#pragma unroll
      for (int j = 0; j < 8; ++j)
        acc[f][j] = __builtin_amdgcn_mfma_f32_16x16x32_bf16(af[f], bf[j], acc[f][j], 0, 0, 0);

#pragma unroll
    for (int f = 0; f < 4; ++f) {
      int nn = h * 4 + f;
      int n = n0 + nn;
      int jv[4];
#pragma unroll
      for (int r = 0; r < 4; ++r) jv[r] = jis[nn * 16 + lhi * 4 + r];  // m = lhi*4+r
      float yv[8][4];
#pragma unroll
      for (int j = 0; j < 8; ++j)
#pragma unroll
        for (int r = 0; r < 4; ++r)
          yv[j][r] = H[(size_t)(hbase + jv[r]) * 1024 + 512 + oc[j]];
      float x1v[8];
#pragma unroll
      for (int j = 0; j < 8; ++j) x1v[j] = x1s[nn][oc[j]];

      if (PASS == 0) {
#pragma unroll
        for (int p = 0; p < 4; ++p) {
#pragma unroll
          for (int r = 0; r < 4; ++r) {
            float zf = acc[f][p][r] + x1v[p] + yv[p][r];
            float zc = acc[f][p + 4][r] + x1v[p + 4] + yv[p + 4][r];
            s1f[p] += zf; s2f[p] = fmaf(zf, zf, s2f[p]);
            s1c[p] += zc; s2c[p] = fmaf(zc, zc, s2c[p]);
          }
        }
      } else {
#pragma unroll
        for (int p = 0; p < 4; ++p) {
          float ps = 0.f;
#pragma unroll
          for (int r = 0; r < 4; ++r) {
            float zf = acc[f][p][r] + x1v[p] + yv[p][r];
            float zc = acc[f][p + 4][r] + x1v[p + 4] + yv[p + 4][r];
            float yfv = fmaf(zf, scf[p], shf[p]);
            float ycv = fmaf(zc, scc[p], shc[p]);
            float sig = 1.0f / (1.0f + __expf(-yfv));
            ps = fmaf(sig, fmaxf(ycv, 0.f), ps);
          }
          ps += __shfl_xor(ps, 16);
          ps += __shfl_xor(ps, 32);
          if (lhi == 0) {
            nbr[(size_t)(b * NA + n) * HA + oc[p]] = ps;
            sB1[p] += ps; sB2[p] = fmaf(ps, ps, sB2[p]);
          }
        }
      }
    }
  }

  if (PASS == 0) {
#pragma unroll
    for (int p = 0; p < 4; ++p) {
      float v;
      v = s1f[p]; v += __shfl_xor(v, 16); v += __shfl_xor(v, 32);
      if (lhi == 0) atomicAdd(&stats[oc[p]], v);
      v = s2f[p]; v += __shfl_xor(v, 16); v += __shfl_xor(v, 32);
      if (lhi == 0) atomicAdd(&stats[512 + oc[p]], v);
      v = s1c[p]; v += __shfl_xor(v, 16); v += __shfl_xor(v, 32);
      if (lhi == 0) atomicAdd(&stats[oc[p + 4]], v);
      v = s2c[p]; v += __shfl_xor(v, 16); v += __shfl_xor(v, 32);
      if (lhi == 0) atomicAdd(&stats[512 + oc[p + 4]], v);
    }
  } else {
#pragma unroll
    for (int p = 0; p < 4; ++p) {
      if (lhi == 0) {
        atomicAdd(&stats[oc[p]], sB1[p]);
        atomicAdd(&stats[256 + oc[p]], sB2[p]);
      }
    }
  }
}

__global__ void finalize1(const float* __restrict__ bn1, const float* __restrict__ g,
                          const float* __restrict__ beta, float* __restrict__ coef) {
  int t = threadIdx.x;  // 512
  const float inv = 1.0f / (float)(NB * NA * NM);
  float mu = bn1[t] * inv;
  float var = bn1[512 + t] * inv - mu * mu;
  float sc = g[t] * rsqrtf(var + EPSB);
  coef[t] = sc;
  coef[512 + t] = beta[t] - mu * sc;
}

__global__ void finalize2(const float* __restrict__ bn2, const float* __restrict__ g,
                          const float* __restrict__ beta, float* __restrict__ coef2) {
  int t = threadIdx.x;  // 256
  const float inv = 1.0f / (float)(NB * NA);
  float mu = bn2[t] * inv;
  float var = bn2[256 + t] * inv - mu * mu;
  float sc = g[t] * rsqrtf(var + EPSB);
  coef2[t] = sc;
  coef2[256 + t] = beta[t] - mu * sc;
}

// pass_c: atom = relu(atom + nbr*sc + sh); emit bf16 copy for next layer's GEMM A
__global__ void pass_c(float4* __restrict__ atom, const float4* __restrict__ nbr,
                       const float* __restrict__ coef2, short* __restrict__ abf) {
  int i = blockIdx.x * 256 + threadIdx.x;
  int o = (i & 63) * 4;
  float4 a = atom[i];
  float4 nv = nbr[i];
  a.x = fmaxf(a.x + fmaf(nv.x, coef2[o + 0], coef2[256 + o + 0]), 0.f);
  a.y = fmaxf(a.y + fmaf(nv.y, coef2[o + 1], coef2[256 + o + 1]), 0.f);
  a.z = fmaxf(a.z + fmaf(nv.z, coef2[o + 2], coef2[256 + o + 2]), 0.f);
  a.w = fmaxf(a.w + fmaf(nv.w, coef2[o + 3], coef2[256 + o + 3]), 0.f);
  atom[i] = a;
  short4 s;
  s.x = f2bf(a.x); s.y = f2bf(a.y); s.z = f2bf(a.z); s.w = f2bf(a.w);
  *(short4*)&abf[(size_t)i * 4] = s;
}

// ---------------- epilogue ----------------
__global__ __launch_bounds__(256) void epilogue(const float* __restrict__ atom,
                                                const float* __restrict__ Wc,
                                                const float* __restrict__ bc,
                                                float* __restrict__ out) {
  __shared__ float pooled[HA];
  __shared__ float lg[NCLS];
  int b = blockIdx.x, t = threadIdx.x;
  float s = 0.f;
  for (int n = 0; n < NA; ++n) s += atom[(size_t)(b * NA + n) * HA + t];
  pooled[t] = s * (1.0f / (float)NA);
  __syncthreads();
  if (t < NCLS) {
    float a = bc[t];
    for (int o = 0; o < HA; ++o) a += pooled[o] * Wc[o * NCLS + t];
    lg[t] = a;
  }
  __syncthreads();
  if (t == 0) {
    float mx = lg[0];
    for (int c = 1; c < NCLS; ++c) mx = fmaxf(mx, lg[c]);
    float e[NCLS], den = 0.f;
    for (int c = 0; c < NCLS; ++c) { e[c] = __expf(lg[c] - mx); den += e[c]; }
    for (int c = 0; c < NCLS; ++c) out[b * NCLS + c] = e[c] / den;
  }
}

extern "C" void kernel_launch(void* const* d_in, const int* in_sizes, int n_in,
                              void* d_out, int out_size, void* d_ws, size_t ws_size,
                              hipStream_t stream) {
  const float* dist = (const float*)d_in[0];
  const int* adj = (const int*)d_in[1];
  const float* emb = (const float*)d_in[2];
  const float* Wf = (const float*)d_in[3];
  const float* gh = (const float*)d_in[5];
  const float* bh = (const float*)d_in[6];
  const float* go = (const float*)d_in[7];
  const float* bo = (const float*)d_in[8];
  const float* Wc = (const float*)d_in[9];
  const float* bc = (const float*)d_in[10];
  float* out = (float*)d_out;

  char* p = (char*)d_ws;
  short* Gbf = (short*)p;   p += (size_t)NB * NA * NM * NF * 2;   // 8 MB
  float* H = (float*)p;     p += (size_t)NB * NA * 1024 * 4;      // 64 MB
  float* H0 = (float*)p;    p += (size_t)NA * 1024 * 4;           // 1 MB
  float* atom = (float*)p;  p += (size_t)NB * NA * HA * 4;        // 16 MB
  float* nbr = (float*)p;   p += (size_t)NB * NA * HA * 4;        // 16 MB
  short* WT = (short*)p;    p += (size_t)NCONV * 1024 * 256 * 2;  // 1.5 MB
  short* Abf = (short*)p;   p += (size_t)NB * NA * 256 * 2;       // 8 MB
  short* Ebf = (short*)p;   p += (size_t)NA * 256 * 2;            // 128 KB
  short* W3bf = (short*)p;  p += (size_t)NCONV * 512 * NF * 2;    // 48 KB
  float* bn1 = (float*)p;   p += 1024 * 4;
  float* bn2 = (float*)p;   p += 512 * 4;
  float* coef1 = (float*)p; p += 1024 * 4;
  float* coef2 = (float*)p; p += 512 * 4;

  prep_weights<<<3072, 256, 0, stream>>>(Wf, WT, W3bf);
  gauss_kernel<<<16384, 256, 0, stream>>>(dist, Gbf);
  init_atom<<<16384, 256, 0, stream>>>(emb, atom);
  emb_bf<<<256, 256, 0, stream>>>(emb, Ebf);

  for (int l = 0; l < NCONV; ++l) {
    hipMemsetAsync(bn1, 0, (1024 + 512) * 4, stream);
    int Mrows = (l == 0) ? NA : NB * NA;
    const short* Amat = (l == 0) ? Ebf : Abf;
    float* Hl = (l == 0) ? H0 : H;
    gemm_mfma<<<(Mrows / 128) * 8, 256, 0, stream>>>(Amat, WT + (size_t)l * 1024 * 256, Hl, Mrows);
    pass_mfma<0><<<2048, 256, 0, stream>>>(Hl, Gbf, adj, W3bf + (size_t)l * 512 * NF,
                                           nullptr, nullptr, bn1, l > 0);
    finalize1<<<1, 512, 0, stream>>>(bn1, gh + l * 512, bh + l * 512, coef1);
    pass_mfma<1><<<2048, 256, 0, stream>>>(Hl, Gbf, adj, W3bf + (size_t)l * 512 * NF,
                                           coef1, nbr, bn2, l > 0);
    finalize2<<<1, 256, 0, stream>>>(bn2, go + l * 256, bo + l * 256, coef2);
    pass_c<<<4096, 256, 0, stream>>>((float4*)atom, (const float4*)nbr, coef2, Abf);
  }
  epilogue<<<NB, 256, 0, stream>>>(atom, Wc, bc, out);
}

// Round 8
// 546.448 us; speedup vs baseline: 1.7339x; 1.0466x over previous
//
#include <hip/hip_runtime.h>
#include <math.h>

#define NB 64
#define NA 256
#define NM 16
#define HA 256
#define NF 16
#define NCONV 3
#define NCLS 6
#define EPSB 1e-5f

typedef __attribute__((ext_vector_type(8))) short short8v;   // 8 bf16 (4 VGPR)
typedef __attribute__((ext_vector_type(4))) float f32x4;

__device__ __forceinline__ short f2bf(float x) {
  union { float f; unsigned u; } v; v.f = x;
  unsigned r = v.u + 0x7fff + ((v.u >> 16) & 1);  // RTNE
  return (short)(r >> 16);
}

// ---------------- prep: WT bf16 [l][1024][256] + W3bf bf16 [l][512 o][16 k] ----------------
__global__ void prep_weights(const float* __restrict__ Wf,
                             short* __restrict__ WT, short* __restrict__ W3bf) {
  int i = blockIdx.x * 256 + threadIdx.x;
  const int TOT1 = NCONV * 1024 * 256;
  if (i < TOT1) {
    int l = i / (1024 * 256);
    int r = i - l * (1024 * 256);
    int o = r >> 8, k = r & 255;
    float w = (o < 512) ? Wf[(l * 528 + k) * 512 + o]
                        : Wf[(l * 528 + 256 + k) * 512 + (o - 512)];
    WT[i] = f2bf(w);
  }
  const int TOT2 = NCONV * 512 * NF;  // [l][o][k]
  if (i < TOT2) {
    int l = i / (512 * NF);
    int r = i - l * (512 * NF);
    int o = r >> 4, k = r & 15;
    W3bf[i] = f2bf(Wf[(l * 528 + 512 + k) * 512 + o]);
  }
}

// Gaussian expansion, bf16 out: Gbf[b,n,m,k] = bf16(exp(-(d - 0.2k)^2/0.04))
__global__ void gauss_kernel(const float* __restrict__ dist, short* __restrict__ Gbf) {
  int i = blockIdx.x * 256 + threadIdx.x;
  int r = i >> 4, f = i & 15;
  float d = dist[r];
  float x = d - 0.2f * (float)f;
  Gbf[i] = f2bf(__expf(-x * x * 25.0f));
}

__global__ void init_atom(const float* __restrict__ emb, float* __restrict__ atom) {
  int i = blockIdx.x * 256 + threadIdx.x;
  atom[i] = emb[i & (NA * HA - 1)];
}

__global__ void emb_bf(const float* __restrict__ emb, short* __restrict__ ebf) {
  int i = blockIdx.x * 256 + threadIdx.x;
  ebf[i] = f2bf(emb[i]);
}

// ---------------- MFMA GEMM: C[M][1024] f32 = Abf[M][256] @ WT^T ----------------
__global__ __launch_bounds__(256) void gemm_mfma(const short* __restrict__ Abf,
                                                 const short* __restrict__ WT,
                                                 float* __restrict__ C, int Mrows) {
  __shared__ short As[128][72];
  __shared__ short Bs[128][72];
  int t = threadIdx.x;
  int wave = t >> 6, lane = t & 63;
  int wr = wave >> 1, wc = wave & 1;
  int l16 = lane & 15, lhi = lane >> 4;

  int wg = blockIdx.x;
  int nRowBlocks = Mrows >> 7;
  int rowBlock, colBlock;
  if (nRowBlocks >= 8) {
    rowBlock = (wg & 7) + ((wg >> 6) << 3);
    colBlock = (wg >> 3) & 7;
  } else {
    rowBlock = wg % nRowBlocks;
    colBlock = wg / nRowBlocks;
  }
  int rowBase = rowBlock << 7, colBase = colBlock << 7;

  f32x4 acc[4][4];
#pragma unroll
  for (int i = 0; i < 4; ++i)
#pragma unroll
    for (int j = 0; j < 4; ++j) acc[i][j] = (f32x4)(0.f);

  for (int k0 = 0; k0 < 256; k0 += 64) {
#pragma unroll
    for (int cc = 0; cc < 4; ++cc) {
      int c = t + cc * 256;
      int row = c >> 3, ko = (c & 7) << 3;
      *(int4*)&As[row][ko] = *(const int4*)&Abf[(size_t)(rowBase + row) * 256 + k0 + ko];
      *(int4*)&Bs[row][ko] = *(const int4*)&WT[(size_t)(colBase + row) * 256 + k0 + ko];
    }
    __syncthreads();
#pragma unroll
    for (int ks = 0; ks < 2; ++ks) {
      int kk = ks * 32 + lhi * 8;
      short8v a[4], b[4];
#pragma unroll
      for (int f = 0; f < 4; ++f) {
        a[f] = *(const short8v*)&As[wr * 64 + f * 16 + l16][kk];
        b[f] = *(const short8v*)&Bs[wc * 64 + f * 16 + l16][kk];
      }
#pragma unroll
      for (int i = 0; i < 4; ++i)
#pragma unroll
        for (int j = 0; j < 4; ++j)
          acc[i][j] = __builtin_amdgcn_mfma_f32_16x16x32_bf16(a[i], b[j], acc[i][j], 0, 0, 0);
    }
    __syncthreads();
  }
#pragma unroll
  for (int i = 0; i < 4; ++i) {
#pragma unroll
    for (int j = 0; j < 4; ++j) {
      int col = colBase + wc * 64 + j * 16 + l16;
      int row0 = rowBase + wr * 64 + i * 16 + lhi * 4;
#pragma unroll
      for (int r = 0; r < 4; ++r)
        C[(size_t)(row0 + r) * 1024 + col] = acc[i][j][r];
    }
  }
}

// ---------------- XCD-swizzled block decode for passes ----------------
__device__ __forceinline__ void decode_wg(int wg, int& b, int& n0) {
  int x = wg & 7;
  int t2 = wg >> 3;
  int ng = t2 & 31;
  int bhi = t2 >> 5;
  b = bhi * 8 + x;
  n0 = ng * 8;
}

// ---------------- unified MFMA pass, occupancy-first ----------------
// PASS=0 -> BN1 stats; PASS=1 -> BN apply + sigmoid*relu + m-sum + BN2 stats.
// No big LDS: W3/G MFMA fragments loaded directly from global (16B chunks),
// k 16..31 zero (K=16 padded to 32). One n per acc batch -> acc[8] (32 regs).
template <int PASS>
__global__ __launch_bounds__(256, 3) void pass_mfma(const float* __restrict__ H,
                                                    const short* __restrict__ Gbf,
                                                    const int* __restrict__ adj,
                                                    const short* __restrict__ W3bf,
                                                    const float* __restrict__ coef,
                                                    float* __restrict__ nbr,
                                                    float* __restrict__ stats,
                                                    int batched) {
  __shared__ int jis[128];
  __shared__ float cf[1024];

  int t = threadIdx.x;
  int b, n0;
  decode_wg(blockIdx.x, b, n0);
  int hbase = batched ? b * NA : 0;

  if (t < 128) jis[t] = adj[(b * NA + n0) * NM + t];
  if (PASS == 1) {
    cf[t] = coef[t]; cf[256 + t] = coef[256 + t];
    cf[512 + t] = coef[512 + t]; cf[768 + t] = coef[768 + t];
  }
  __syncthreads();

  int lane = t & 63, wv = t >> 6;
  int l16 = lane & 15, lhi = lane >> 4;
  const short8v zv = {0, 0, 0, 0, 0, 0, 0, 0};

  // B-fragments direct from global: col oc[j], k = lhi*8 (lhi<2), else zero pad
  short8v bfm[8];
  int oc[8];
#pragma unroll
  for (int j = 0; j < 8; ++j) {
    int col = wv * 64 + (j & 3) * 16 + l16 + ((j >= 4) ? 256 : 0);
    oc[j] = col;
    bfm[j] = (lhi < 2) ? *(const short8v*)&W3bf[(size_t)col * NF + lhi * 8] : zv;
  }

  float scf[4], shf[4], scc[4], shc[4];
  if (PASS == 1) {
#pragma unroll
    for (int p = 0; p < 4; ++p) {
      scf[p] = cf[oc[p]];       shf[p] = cf[512 + oc[p]];
      scc[p] = cf[oc[p + 4]];   shc[p] = cf[512 + oc[p + 4]];
    }
  }

  float s1f[4] = {0, 0, 0, 0}, s2f[4] = {0, 0, 0, 0};
  float s1c[4] = {0, 0, 0, 0}, s2c[4] = {0, 0, 0, 0};
  float sB1[4] = {0, 0, 0, 0}, sB2[4] = {0, 0, 0, 0};

  for (int nn = 0; nn < 8; ++nn) {
    int n = n0 + nn;
    // A-fragment direct from global: rows m = l16 of G for this n
    short8v af = (lhi < 2)
        ? *(const short8v*)&Gbf[(((size_t)(b * NA + n)) * NM + l16) * NF + lhi * 8]
        : zv;
    f32x4 acc[8];
#pragma unroll
    for (int j = 0; j < 8; ++j) acc[j] = (f32x4)(0.f);
#pragma unroll
    for (int j = 0; j < 8; ++j)
      acc[j] = __builtin_amdgcn_mfma_f32_16x16x32_bf16(af, bfm[j], acc[j], 0, 0, 0);

    int jv[4];
#pragma unroll
    for (int r = 0; r < 4; ++r) jv[r] = jis[nn * 16 + lhi * 4 + r];  // m = lhi*4+r
    const float* hs = &H[(size_t)(hbase + n) * 1024];
    float x1v[8];
#pragma unroll
    for (int j = 0; j < 8; ++j) x1v[j] = hs[oc[j]];
    float yv[8][4];
#pragma unroll
    for (int j = 0; j < 8; ++j)
#pragma unroll
      for (int r = 0; r < 4; ++r)
        yv[j][r] = H[(size_t)(hbase + jv[r]) * 1024 + 512 + oc[j]];

    if (PASS == 0) {
#pragma unroll
      for (int p = 0; p < 4; ++p) {
#pragma unroll
        for (int r = 0; r < 4; ++r) {
          float zf = acc[p][r] + x1v[p] + yv[p][r];
          float zc = acc[p + 4][r] + x1v[p + 4] + yv[p + 4][r];
          s1f[p] += zf; s2f[p] = fmaf(zf, zf, s2f[p]);
          s1c[p] += zc; s2c[p] = fmaf(zc, zc, s2c[p]);
        }
      }
    } else {
#pragma unroll
      for (int p = 0; p < 4; ++p) {
        float ps = 0.f;
#pragma unroll
        for (int r = 0; r < 4; ++r) {
          float zf = acc[p][r] + x1v[p] + yv[p][r];
          float zc = acc[p + 4][r] + x1v[p + 4] + yv[p + 4][r];
          float yfv = fmaf(zf, scf[p], shf[p]);
          float ycv = fmaf(zc, scc[p], shc[p]);
          float sig = 1.0f / (1.0f + __expf(-yfv));
          ps = fmaf(sig, fmaxf(ycv, 0.f), ps);
        }
        ps += __shfl_xor(ps, 16);
        ps += __shfl_xor(ps, 32);
        if (lhi == 0) {
          nbr[(size_t)(b * NA + n) * HA + oc[p]] = ps;
          sB1[p] += ps; sB2[p] = fmaf(ps, ps, sB2[p]);
        }
      }
    }
  }

  if (PASS == 0) {
#pragma unroll
    for (int p = 0; p < 4; ++p) {
      float v;
      v = s1f[p]; v += __shfl_xor(v, 16); v += __shfl_xor(v, 32);
      if (lhi == 0) atomicAdd(&stats[oc[p]], v);
      v = s2f[p]; v += __shfl_xor(v, 16); v += __shfl_xor(v, 32);
      if (lhi == 0) atomicAdd(&stats[512 + oc[p]], v);
      v = s1c[p]; v += __shfl_xor(v, 16); v += __shfl_xor(v, 32);
      if (lhi == 0) atomicAdd(&stats[oc[p + 4]], v);
      v = s2c[p]; v += __shfl_xor(v, 16); v += __shfl_xor(v, 32);
      if (lhi == 0) atomicAdd(&stats[512 + oc[p + 4]], v);
    }
  } else {
#pragma unroll
    for (int p = 0; p < 4; ++p) {
      if (lhi == 0) {
        atomicAdd(&stats[oc[p]], sB1[p]);
        atomicAdd(&stats[256 + oc[p]], sB2[p]);
      }
    }
  }
}

__global__ void finalize1(const float* __restrict__ bn1, const float* __restrict__ g,
                          const float* __restrict__ beta, float* __restrict__ coef) {
  int t = threadIdx.x;  // 512
  const float inv = 1.0f / (float)(NB * NA * NM);
  float mu = bn1[t] * inv;
  float var = bn1[512 + t] * inv - mu * mu;
  float sc = g[t] * rsqrtf(var + EPSB);
  coef[t] = sc;
  coef[512 + t] = beta[t] - mu * sc;
}

__global__ void finalize2(const float* __restrict__ bn2, const float* __restrict__ g,
                          const float* __restrict__ beta, float* __restrict__ coef2) {
  int t = threadIdx.x;  // 256
  const float inv = 1.0f / (float)(NB * NA);
  float mu = bn2[t] * inv;
  float var = bn2[256 + t] * inv - mu * mu;
  float sc = g[t] * rsqrtf(var + EPSB);
  coef2[t] = sc;
  coef2[256 + t] = beta[t] - mu * sc;
}

// pass_c: atom = relu(atom + nbr*sc + sh); emit bf16 copy for next layer's GEMM A
__global__ void pass_c(float4* __restrict__ atom, const float4* __restrict__ nbr,
                       const float* __restrict__ coef2, short* __restrict__ abf) {
  int i = blockIdx.x * 256 + threadIdx.x;
  int o = (i & 63) * 4;
  float4 a = atom[i];
  float4 nv = nbr[i];
  a.x = fmaxf(a.x + fmaf(nv.x, coef2[o + 0], coef2[256 + o + 0]), 0.f);
  a.y = fmaxf(a.y + fmaf(nv.y, coef2[o + 1], coef2[256 + o + 1]), 0.f);
  a.z = fmaxf(a.z + fmaf(nv.z, coef2[o + 2], coef2[256 + o + 2]), 0.f);
  a.w = fmaxf(a.w + fmaf(nv.w, coef2[o + 3], coef2[256 + o + 3]), 0.f);
  atom[i] = a;
  short4 s;
  s.x = f2bf(a.x); s.y = f2bf(a.y); s.z = f2bf(a.z); s.w = f2bf(a.w);
  *(short4*)&abf[(size_t)i * 4] = s;
}

// ---------------- epilogue ----------------
__global__ __launch_bounds__(256) void epilogue(const float* __restrict__ atom,
                                                const float* __restrict__ Wc,
                                                const float* __restrict__ bc,
                                                float* __restrict__ out) {
  __shared__ float pooled[HA];
  __shared__ float lg[NCLS];
  int b = blockIdx.x, t = threadIdx.x;
  float s = 0.f;
  for (int n = 0; n < NA; ++n) s += atom[(size_t)(b * NA + n) * HA + t];
  pooled[t] = s * (1.0f / (float)NA);
  __syncthreads();
  if (t < NCLS) {
    float a = bc[t];
    for (int o = 0; o < HA; ++o) a += pooled[o] * Wc[o * NCLS + t];
    lg[t] = a;
  }
  __syncthreads();
  if (t == 0) {
    float mx = lg[0];
    for (int c = 1; c < NCLS; ++c) mx = fmaxf(mx, lg[c]);
    float e[NCLS], den = 0.f;
    for (int c = 0; c < NCLS; ++c) { e[c] = __expf(lg[c] - mx); den += e[c]; }
    for (int c = 0; c < NCLS; ++c) out[b * NCLS + c] = e[c] / den;
  }
}

extern "C" void kernel_launch(void* const* d_in, const int* in_sizes, int n_in,
                              void* d_out, int out_size, void* d_ws, size_t ws_size,
                              hipStream_t stream) {
  const float* dist = (const float*)d_in[0];
  const int* adj = (const int*)d_in[1];
  const float* emb = (const float*)d_in[2];
  const float* Wf = (const float*)d_in[3];
  const float* gh = (const float*)d_in[5];
  const float* bh = (const float*)d_in[6];
  const float* go = (const float*)d_in[7];
  const float* bo = (const float*)d_in[8];
  const float* Wc = (const float*)d_in[9];
  const float* bc = (const float*)d_in[10];
  float* out = (float*)d_out;

  char* p = (char*)d_ws;
  short* Gbf = (short*)p;   p += (size_t)NB * NA * NM * NF * 2;   // 8 MB
  float* H = (float*)p;     p += (size_t)NB * NA * 1024 * 4;      // 64 MB
  float* H0 = (float*)p;    p += (size_t)NA * 1024 * 4;           // 1 MB
  float* atom = (float*)p;  p += (size_t)NB * NA * HA * 4;        // 16 MB
  float* nbr = (float*)p;   p += (size_t)NB * NA * HA * 4;        // 16 MB
  short* WT = (short*)p;    p += (size_t)NCONV * 1024 * 256 * 2;  // 1.5 MB
  short* Abf = (short*)p;   p += (size_t)NB * NA * 256 * 2;       // 8 MB
  short* Ebf = (short*)p;   p += (size_t)NA * 256 * 2;            // 128 KB
  short* W3bf = (short*)p;  p += (size_t)NCONV * 512 * NF * 2;    // 48 KB
  float* bn1 = (float*)p;   p += 1024 * 4;
  float* bn2 = (float*)p;   p += 512 * 4;
  float* coef1 = (float*)p; p += 1024 * 4;
  float* coef2 = (float*)p; p += 512 * 4;

  prep_weights<<<3072, 256, 0, stream>>>(Wf, WT, W3bf);
  gauss_kernel<<<16384, 256, 0, stream>>>(dist, Gbf);
  init_atom<<<16384, 256, 0, stream>>>(emb, atom);
  emb_bf<<<256, 256, 0, stream>>>(emb, Ebf);

  for (int l = 0; l < NCONV; ++l) {
    hipMemsetAsync(bn1, 0, (1024 + 512) * 4, stream);
    int Mrows = (l == 0) ? NA : NB * NA;
    const short* Amat = (l == 0) ? Ebf : Abf;
    float* Hl = (l == 0) ? H0 : H;
    gemm_mfma<<<(Mrows / 128) * 8, 256, 0, stream>>>(Amat, WT + (size_t)l * 1024 * 256, Hl, Mrows);
    pass_mfma<0><<<2048, 256, 0, stream>>>(Hl, Gbf, adj, W3bf + (size_t)l * 512 * NF,
                                           nullptr, nullptr, bn1, l > 0);
    finalize1<<<1, 512, 0, stream>>>(bn1, gh + l * 512, bh + l * 512, coef1);
    pass_mfma<1><<<2048, 256, 0, stream>>>(Hl, Gbf, adj, W3bf + (size_t)l * 512 * NF,
                                           coef1, nbr, bn2, l > 0);
    finalize2<<<1, 256, 0, stream>>>(bn2, go + l * 256, bo + l * 256, coef2);
    pass_c<<<4096, 256, 0, stream>>>((float4*)atom, (const float4*)nbr, coef2, Abf);
  }
  epilogue<<<NB, 256, 0, stream>>>(atom, Wc, bc, out);
}